// Round 6
// baseline (167.843 us; speedup 1.0000x reference)
//
#include <hip/hip_runtime.h>

#define NUM_GRAPHS 512
#define NPG 200      // nodes per graph
#define EPG 3200     // edges per graph
#define NROIS 200    // input feature dim
#define HID 64
#define OUTC 2
#define NT (NUM_GRAPHS * NPG)   // 102400 total nodes
#define APITCH 232   // adjacency row pitch (bytes)
#define HPITCH 232   // bf16 row pitch (elements); 464 B = 116 dw, 116%32=20 -> 2-way (free)
#define WIMG_ELEMS (7 * 4 * 2 * 64 * 8)          // 28672 ushorts = 57344 B
#define WS_NEEDED ((size_t)WIMG_ELEMS * 2 + (size_t)HID * NT * 2)

typedef short v8s __attribute__((ext_vector_type(8)));
typedef float v4f __attribute__((ext_vector_type(4)));

__device__ __forceinline__ unsigned bf16_rne(float f) {
  unsigned u = __float_as_uint(f);
  return (u + 0x7fffu + ((u >> 16) & 1u)) >> 16;
}

// ============ prep: W -> bf16 hi/lo fragment-order image ============
// layout: idx = (((kt*4+nt)*2+hl)*64 + lane)*8 + i  -> coalesced 1KB frag loads
__global__ void prep_wimg(const float* __restrict__ cw, unsigned short* __restrict__ wimg) {
  int idx = blockIdx.x * 256 + threadIdx.x;
  if (idx >= WIMG_ELEMS) return;
  int i    = idx & 7;
  int lane = (idx >> 3) & 63;
  int hl   = (idx >> 9) & 1;
  int nt   = (idx >> 10) & 3;
  int kt   = idx >> 12;
  int k  = kt * 32 + (lane >> 4) * 8 + i;
  int ch = nt * 16 + (lane & 15);
  float f = (k < NROIS) ? cw[k * HID + ch] : 0.f;
  unsigned hi = bf16_rne(f);
  float lo = f - __uint_as_float(hi << 16);
  wimg[idx] = hl ? (unsigned short)(__float_as_uint(lo) >> 16) : (unsigned short)hi;
}

// ============ kernel 1: H^T = (X @ W)^T as bf16 into ws ============
// block = 64-node M-tile; x staged in LDS (hi/lo bf16); W from fragment image.
struct __align__(16) Smem1 {
  unsigned short xhi[64 * HPITCH];
  unsigned short xlo[64 * HPITCH];
};

__global__ __launch_bounds__(256, 2)
void gcn_gemm1(const float* __restrict__ x,
               const unsigned short* __restrict__ wimg,
               unsigned short* __restrict__ hpT) {
  __shared__ Smem1 s;
  const int tid = threadIdx.x;
  const int blk = blockIdx.x;                 // 0..1599
  const int lane = tid & 63;
  const int w = __builtin_amdgcn_readfirstlane(tid >> 6);   // 0..3
  const int ml = tid & 15;
  const int q  = (tid >> 4) & 3;

  // ---- stage x[64 nodes][200] -> LDS bf16 hi/lo (coalesced float4 reads) ----
  #pragma unroll
  for (int t = 0; t < 13; ++t) {
    int i = tid + t * 256;
    if (i < 3200) {
      int node = i / 50;
      int kc = (i - node * 50) * 4;
      const float4 v = *(const float4*)(x + (size_t)(blk * 64 + node) * NROIS + kc);
      const float ff[4] = {v.x, v.y, v.z, v.w};
      unsigned hh[4], ll[4];
      #pragma unroll
      for (int e = 0; e < 4; ++e) {
        unsigned u = __float_as_uint(ff[e]);
        hh[e] = u >> 16;                                   // trunc hi
        float lo = ff[e] - __uint_as_float(hh[e] << 16);
        ll[e] = __float_as_uint(lo) >> 16;                 // trunc lo
      }
      uint2 ph = {hh[0] | (hh[1] << 16), hh[2] | (hh[3] << 16)};
      uint2 pl = {ll[0] | (ll[1] << 16), ll[2] | (ll[3] << 16)};
      *(uint2*)&s.xhi[node * HPITCH + kc] = ph;
      *(uint2*)&s.xlo[node * HPITCH + kc] = pl;
    }
  }
  // zero pad cols [200,232) so kt=6 (reads up to col 223) is clean
  for (int i = tid; i < 64 * 32; i += 256) {
    int node = i >> 5, c = 200 + (i & 31);
    s.xhi[node * HPITCH + c] = 0;
    s.xlo[node * HPITCH + c] = 0;
  }
  __syncthreads();

  // ---- GEMM: A = W (m=ch), B = x (n=node); wave w owns nodes w*16..+16 ----
  v4f acc[4];
  #pragma unroll
  for (int nt = 0; nt < 4; ++nt) acc[nt] = (v4f){0.f, 0.f, 0.f, 0.f};

  for (int kt = 0; kt < 7; ++kt) {
    const int k0 = kt * 32 + q * 8;
    const v8s xh = *(const v8s*)&s.xhi[(w * 16 + ml) * HPITCH + k0];
    const v8s xl = *(const v8s*)&s.xlo[(w * 16 + ml) * HPITCH + k0];
    #pragma unroll
    for (int nt = 0; nt < 4; ++nt) {
      const unsigned short* pw = wimg + (size_t)(((kt * 4 + nt) * 2) * 64 + lane) * 8;
      const v8s whi = *(const v8s*)pw;            // coalesced 1KB wave load
      const v8s wlo = *(const v8s*)(pw + 64 * 8);
      acc[nt] = __builtin_amdgcn_mfma_f32_16x16x32_bf16(whi, xl, acc[nt], 0, 0, 0);
      acc[nt] = __builtin_amdgcn_mfma_f32_16x16x32_bf16(wlo, xh, acc[nt], 0, 0, 0);
      acc[nt] = __builtin_amdgcn_mfma_f32_16x16x32_bf16(whi, xh, acc[nt], 0, 0, 0);
    }
  }

  // ---- store D[ch][node] -> hpT[ch][gnode] (bf16) ----
  const int gnode = blk * 64 + w * 16 + ml;
  #pragma unroll
  for (int nt = 0; nt < 4; ++nt) {
    #pragma unroll
    for (int r = 0; r < 4; ++r) {
      const int ch = nt * 16 + q * 4 + r;
      hpT[(size_t)ch * NT + gnode] = (unsigned short)bf16_rne(acc[nt][r]);
    }
  }
}

// ============ kernel 2: adjacency + AGG = (A+I)@hp + relu + pool + linear ============
// LDS: 48256 + 29696 + 800 + 800 + 256 = 79808 B -> 2 blocks/CU
struct __align__(16) Smem2 {
  unsigned char adj[208 * APITCH];   // (A+I) counts as bytes (zero-padded)
  unsigned short hpTl[HID * HPITCH]; // bf16 dinv[src]*h[src][ch], [ch][src]
  float dinv[NPG];
  int cnt[NPG];
  int pool[HID];
};

__global__ __launch_bounds__(512, 4)
void gcn_agg(const int* __restrict__ ei,
             const unsigned short* __restrict__ hpT,
             const float* __restrict__ cb,
             const float* __restrict__ lw,
             const float* __restrict__ lb,
             float* __restrict__ out,
             int Etot) {
  __shared__ Smem2 s;
  const int g = blockIdx.x;
  const int tid = threadIdx.x;
  const int base = g * NPG;
  const int ebase = g * EPG;
  const int lane = tid & 63;
  const int w = __builtin_amdgcn_readfirstlane(tid >> 6);  // 0..7
  const int ml = tid & 15;
  const int q  = (tid >> 4) & 3;

  // ---- phase 0: zero adj + hpTl, cnt, pool ----
  {
    uint4* z = (uint4*)&s;
    const uint4 z4 = {0u, 0u, 0u, 0u};
    #pragma unroll
    for (int i = 0; i < 10; ++i) {
      int idx = tid + i * 512;
      if (idx < (208 * APITCH + HID * HPITCH * 2) / 16) z[idx] = z4;
    }
    if (tid < NPG) s.cnt[tid] = 0;
    if (tid < HID) s.pool[tid] = 0;   // relu >= 0 -> 0 is identity for max
  }
  __syncthreads();

  // ---- phase A: edges -> regs + in-degree count ----
  int esrc[7], edst[7];
  #pragma unroll
  for (int r = 0; r < 7; ++r) {
    int e = tid + r * 512;
    esrc[r] = -1; edst[r] = 0;
    if (e < EPG) {
      esrc[r] = ei[ebase + e] - base;
      edst[r] = ei[Etot + ebase + e] - base;
      atomicAdd(&s.cnt[edst[r]], 1);
    }
  }
  __syncthreads();

  // ---- phase B: dinv ----
  if (tid < NPG) s.dinv[tid] = rsqrtf((float)(s.cnt[tid] + 1));
  __syncthreads();

  // ---- phase C: scatter (A+I) counts (dup-safe packed byte atomics) ----
  {
    unsigned* adjW = (unsigned*)s.adj;
    #pragma unroll
    for (int r = 0; r < 7; ++r) {
      if (esrc[r] >= 0) {
        int idx = edst[r] * APITCH + esrc[r];
        atomicAdd(&adjW[idx >> 2], 1u << ((idx & 3) * 8));
      }
    }
    if (tid < NPG) {
      int idx = tid * APITCH + tid;
      atomicAdd(&adjW[idx >> 2], 1u << ((idx & 3) * 8));
    }
  }

  // ---- phase D': stage hpT tile, scaled by dinv[src] (coalesced dword reads) ----
  #pragma unroll
  for (int t = 0; t < 13; ++t) {
    int i = tid + t * 512;
    if (i < HID * 100) {
      int ch = i / 100;
      int c2 = (i - ch * 100) * 2;
      unsigned v = *(const unsigned*)(hpT + (size_t)ch * NT + base + c2);
      float f0 = __uint_as_float(v << 16)         * s.dinv[c2];
      float f1 = __uint_as_float(v & 0xffff0000u) * s.dinv[c2 + 1];
      *(unsigned*)&s.hpTl[ch * HPITCH + c2] = bf16_rne(f0) | (bf16_rne(f1) << 16);
    }
  }
  __syncthreads();   // adj + hpTl ready

  // ---- phase E: AGG = (A+I) @ hp via bf16 MFMA (counts exact in bf16) ----
  {
    int mts[2];
    mts[0] = w;
    mts[1] = (w < 5) ? 8 + w : -1;

    v4f acc2[2][4];
    #pragma unroll
    for (int a = 0; a < 2; ++a)
      #pragma unroll
      for (int b = 0; b < 4; ++b)
        acc2[a][b] = (v4f){0.f, 0.f, 0.f, 0.f};

    for (int kt = 0; kt < 7; ++kt) {
      const int k0 = kt * 32 + q * 8;

      v8s bf[4];
      #pragma unroll
      for (int nt = 0; nt < 4; ++nt)
        bf[nt] = *(const v8s*)&s.hpTl[(nt * 16 + ml) * HPITCH + k0];

      #pragma unroll
      for (int mi = 0; mi < 2; ++mi) {
        if (mts[mi] >= 0) {
          const int row = mts[mi] * 16 + ml;
          const uint2 dd = *(const uint2*)&s.adj[row * APITCH + k0];
          v8s af;
          #pragma unroll
          for (int i = 0; i < 4; ++i) {
            af[i]     = (short)(__float_as_uint((float)((dd.x >> (8 * i)) & 0xffu)) >> 16);
            af[i + 4] = (short)(__float_as_uint((float)((dd.y >> (8 * i)) & 0xffu)) >> 16);
          }
          #pragma unroll
          for (int nt = 0; nt < 4; ++nt)
            acc2[mi][nt] = __builtin_amdgcn_mfma_f32_16x16x32_bf16(af, bf[nt], acc2[mi][nt], 0, 0, 0);
        }
      }
    }

    // epilogue: relu(dinv[dst]*agg + cb) -> max-pool
    float cbv[4];
    #pragma unroll
    for (int nt = 0; nt < 4; ++nt) cbv[nt] = cb[nt * 16 + ml];
    float mx[4] = {0.f, 0.f, 0.f, 0.f};
    #pragma unroll
    for (int mi = 0; mi < 2; ++mi) {
      if (mts[mi] >= 0) {
        #pragma unroll
        for (int r = 0; r < 4; ++r) {
          const int row = mts[mi] * 16 + q * 4 + r;
          if (row < NPG) {
            const float dv = s.dinv[row];
            #pragma unroll
            for (int nt = 0; nt < 4; ++nt) {
              float v = fmaxf(fmaf(dv, acc2[mi][nt][r], cbv[nt]), 0.f);
              mx[nt] = fmaxf(mx[nt], v);
            }
          }
        }
      }
    }
    #pragma unroll
    for (int nt = 0; nt < 4; ++nt) {
      mx[nt] = fmaxf(mx[nt], __shfl_xor(mx[nt], 16));
      mx[nt] = fmaxf(mx[nt], __shfl_xor(mx[nt], 32));
    }
    if (q == 0 && (lane >> 5) == 0) {
      #pragma unroll
      for (int nt = 0; nt < 4; ++nt)
        atomicMax(&s.pool[nt * 16 + ml], __float_as_int(mx[nt]));
    }
  }
  __syncthreads();

  // ---- phase F: write x_pool and out ----
  if (tid < HID) {
    const float xp = __int_as_float(s.pool[tid]);
    out[NUM_GRAPHS * OUTC + g * HID + tid] = xp;
    float p0 = xp * lw[tid * 2 + 0];
    float p1 = xp * lw[tid * 2 + 1];
    #pragma unroll
    for (int off = 32; off > 0; off >>= 1) {
      p0 += __shfl_down(p0, off);
      p1 += __shfl_down(p1, off);
    }
    if (tid == 0) {
      out[g * OUTC + 0] = p0 + lb[0];
      out[g * OUTC + 1] = p1 + lb[1];
    }
  }
}

// ============ fallback: R4 fused kernel (used only if ws too small) ============
struct __align__(16) SmemF {
  unsigned char adj[208 * APITCH];
  unsigned short hpT[HID * HPITCH];
  float dinv[NPG];
  int cnt[NPG];
  int pool[HID];
};

__global__ __launch_bounds__(512, 4)
void gcn_fused_fb(const float* __restrict__ x,
                  const int* __restrict__ ei,
                  const float* __restrict__ cw,
                  const float* __restrict__ cb,
                  const float* __restrict__ lw,
                  const float* __restrict__ lb,
                  float* __restrict__ out,
                  int Etot) {
  __shared__ SmemF s;
  const int g = blockIdx.x;
  const int tid = threadIdx.x;
  const int base = g * NPG;
  const int ebase = g * EPG;
  const int lane = tid & 63;
  const int w = __builtin_amdgcn_readfirstlane(tid >> 6);
  const int ml = tid & 15;
  const int q  = (tid >> 4) & 3;

  {
    uint4* z = (uint4*)&s;
    const uint4 z4 = {0u, 0u, 0u, 0u};
    #pragma unroll
    for (int i = 0; i < 10; ++i) {
      int idx = tid + i * 512;
      if (idx < (208 * APITCH + HID * HPITCH * 2) / 16) z[idx] = z4;
    }
    if (tid < NPG) s.cnt[tid] = 0;
    if (tid < HID) s.pool[tid] = 0;
  }
  __syncthreads();

  int esrc[7], edst[7];
  #pragma unroll
  for (int r = 0; r < 7; ++r) {
    int e = tid + r * 512;
    esrc[r] = -1; edst[r] = 0;
    if (e < EPG) {
      esrc[r] = ei[ebase + e] - base;
      edst[r] = ei[Etot + ebase + e] - base;
      atomicAdd(&s.cnt[edst[r]], 1);
    }
  }
  __syncthreads();

  if (tid < NPG) s.dinv[tid] = rsqrtf((float)(s.cnt[tid] + 1));

  {
    unsigned* adjW = (unsigned*)s.adj;
    #pragma unroll
    for (int r = 0; r < 7; ++r) {
      if (esrc[r] >= 0) {
        int idx = edst[r] * APITCH + esrc[r];
        atomicAdd(&adjW[idx >> 2], 1u << ((idx & 3) * 8));
      }
    }
    if (tid < NPG) {
      int idx = tid * APITCH + tid;
      atomicAdd(&adjW[idx >> 2], 1u << ((idx & 3) * 8));
    }
  }
  __syncthreads();

  {
    int mts[2];
    mts[0] = w;
    mts[1] = (w < 5) ? 8 + w : -1;
    v4f acc[2][4];
    #pragma unroll
    for (int a = 0; a < 2; ++a)
      #pragma unroll
      for (int b = 0; b < 4; ++b)
        acc[a][b] = (v4f){0.f, 0.f, 0.f, 0.f};

    for (int kt = 0; kt < 7; ++kt) {
      const int k0 = kt * 32 + q * 8;
      const bool kok = (k0 < NROIS);
      v8s bhi[4], blo[4];
      #pragma unroll
      for (int nt = 0; nt < 4; ++nt) {
        #pragma unroll
        for (int i = 0; i < 8; ++i) {
          float f = kok ? cw[(k0 + i) * HID + nt * 16 + ml] : 0.f;
          unsigned hb = bf16_rne(f);
          float lo = f - __uint_as_float(hb << 16);
          bhi[nt][i] = (short)hb;
          blo[nt][i] = (short)(__float_as_uint(lo) >> 16);
        }
      }
      #pragma unroll
      for (int mi = 0; mi < 2; ++mi) {
        if (mts[mi] >= 0) {
          const int row = mts[mi] * 16 + ml;
          v8s ahi, alo;
          if (kok && row < NPG) {
            const float* px = x + (size_t)(base + row) * NROIS + k0;
            const float4 f0 = *(const float4*)px;
            const float4 f1 = *(const float4*)(px + 4);
            const float ff[8] = {f0.x, f0.y, f0.z, f0.w, f1.x, f1.y, f1.z, f1.w};
            #pragma unroll
            for (int i = 0; i < 8; ++i) {
              unsigned u = __float_as_uint(ff[i]);
              unsigned hb = u >> 16;
              float lo = ff[i] - __uint_as_float(hb << 16);
              ahi[i] = (short)hb;
              alo[i] = (short)(__float_as_uint(lo) >> 16);
            }
          } else {
            #pragma unroll
            for (int i = 0; i < 8; ++i) { ahi[i] = 0; alo[i] = 0; }
          }
          #pragma unroll
          for (int nt = 0; nt < 4; ++nt) {
            acc[mi][nt] = __builtin_amdgcn_mfma_f32_16x16x32_bf16(ahi, blo[nt], acc[mi][nt], 0, 0, 0);
            acc[mi][nt] = __builtin_amdgcn_mfma_f32_16x16x32_bf16(alo, bhi[nt], acc[mi][nt], 0, 0, 0);
            acc[mi][nt] = __builtin_amdgcn_mfma_f32_16x16x32_bf16(ahi, bhi[nt], acc[mi][nt], 0, 0, 0);
          }
        }
      }
    }
    #pragma unroll
    for (int mi = 0; mi < 2; ++mi) {
      if (mts[mi] >= 0) {
        #pragma unroll
        for (int r = 0; r < 4; ++r) {
          const int row = mts[mi] * 16 + q * 4 + r;
          if (row < NPG) {
            const float dv = s.dinv[row];
            #pragma unroll
            for (int nt = 0; nt < 4; ++nt)
              s.hpT[(nt * 16 + ml) * HPITCH + row] =
                  (unsigned short)bf16_rne(dv * acc[mi][nt][r]);
          }
        }
      }
    }
  }
  __syncthreads();

  {
    int mts[2];
    mts[0] = w;
    mts[1] = (w < 5) ? 8 + w : -1;
    v4f acc2[2][4];
    #pragma unroll
    for (int a = 0; a < 2; ++a)
      #pragma unroll
      for (int b = 0; b < 4; ++b)
        acc2[a][b] = (v4f){0.f, 0.f, 0.f, 0.f};

    for (int kt = 0; kt < 7; ++kt) {
      const int k0 = kt * 32 + q * 8;
      v8s bf[4];
      #pragma unroll
      for (int nt = 0; nt < 4; ++nt)
        bf[nt] = *(const v8s*)&s.hpT[(nt * 16 + ml) * HPITCH + k0];
      #pragma unroll
      for (int mi = 0; mi < 2; ++mi) {
        if (mts[mi] >= 0) {
          const int row = mts[mi] * 16 + ml;
          const uint2 dd = *(const uint2*)&s.adj[row * APITCH + k0];
          v8s af;
          #pragma unroll
          for (int i = 0; i < 4; ++i) {
            af[i]     = (short)(__float_as_uint((float)((dd.x >> (8 * i)) & 0xffu)) >> 16);
            af[i + 4] = (short)(__float_as_uint((float)((dd.y >> (8 * i)) & 0xffu)) >> 16);
          }
          #pragma unroll
          for (int nt = 0; nt < 4; ++nt)
            acc2[mi][nt] = __builtin_amdgcn_mfma_f32_16x16x32_bf16(af, bf[nt], acc2[mi][nt], 0, 0, 0);
        }
      }
    }

    float cbv[4];
    #pragma unroll
    for (int nt = 0; nt < 4; ++nt) cbv[nt] = cb[nt * 16 + ml];
    float mx[4] = {0.f, 0.f, 0.f, 0.f};
    #pragma unroll
    for (int mi = 0; mi < 2; ++mi) {
      if (mts[mi] >= 0) {
        #pragma unroll
        for (int r = 0; r < 4; ++r) {
          const int row = mts[mi] * 16 + q * 4 + r;
          if (row < NPG) {
            const float dv = s.dinv[row];
            #pragma unroll
            for (int nt = 0; nt < 4; ++nt) {
              float v = fmaxf(fmaf(dv, acc2[mi][nt][r], cbv[nt]), 0.f);
              mx[nt] = fmaxf(mx[nt], v);
            }
          }
        }
      }
    }
    #pragma unroll
    for (int nt = 0; nt < 4; ++nt) {
      mx[nt] = fmaxf(mx[nt], __shfl_xor(mx[nt], 16));
      mx[nt] = fmaxf(mx[nt], __shfl_xor(mx[nt], 32));
    }
    if (q == 0 && (lane >> 5) == 0) {
      #pragma unroll
      for (int nt = 0; nt < 4; ++nt)
        atomicMax(&s.pool[nt * 16 + ml], __float_as_int(mx[nt]));
    }
  }
  __syncthreads();

  if (tid < HID) {
    const float xp = __int_as_float(s.pool[tid]);
    out[NUM_GRAPHS * OUTC + g * HID + tid] = xp;
    float p0 = xp * lw[tid * 2 + 0];
    float p1 = xp * lw[tid * 2 + 1];
    #pragma unroll
    for (int off = 32; off > 0; off >>= 1) {
      p0 += __shfl_down(p0, off);
      p1 += __shfl_down(p1, off);
    }
    if (tid == 0) {
      out[g * OUTC + 0] = p0 + lb[0];
      out[g * OUTC + 1] = p1 + lb[1];
    }
  }
}

extern "C" void kernel_launch(void* const* d_in, const int* in_sizes, int n_in,
                              void* d_out, int out_size, void* d_ws, size_t ws_size,
                              hipStream_t stream) {
  const float* x  = (const float*)d_in[0];
  const int*   ei = (const int*)d_in[1];
  // d_in[2] = batch (node/200 by construction; unused)
  const float* cw = (const float*)d_in[3];
  const float* cb = (const float*)d_in[4];
  const float* lw = (const float*)d_in[5];
  const float* lb = (const float*)d_in[6];
  const int Etot = in_sizes[1] / 2;

  if (ws_size >= WS_NEEDED) {
    unsigned short* wimg = (unsigned short*)d_ws;
    unsigned short* hpT  = wimg + WIMG_ELEMS;
    prep_wimg<<<(WIMG_ELEMS + 255) / 256, 256, 0, stream>>>(cw, wimg);
    gcn_gemm1<<<NT / 64, 256, 0, stream>>>(x, wimg, hpT);
    gcn_agg<<<NUM_GRAPHS, 512, 0, stream>>>(ei, hpT, cb, lw, lb, (float*)d_out, Etot);
  } else {
    gcn_fused_fb<<<NUM_GRAPHS, 512, 0, stream>>>(x, ei, cw, cb, lw, lb,
                                                 (float*)d_out, Etot);
  }
}

// Round 7
// 154.464 us; speedup vs baseline: 1.0866x; 1.0866x over previous
//
#include <hip/hip_runtime.h>

#define NUM_GRAPHS 512
#define NPG 200      // nodes per graph
#define EPG 3200     // edges per graph
#define NROIS 200    // input feature dim
#define HID 64
#define OUTC 2
#define APITCH 232   // adjacency row pitch (bytes)
#define HPITCH 232   // hpTl row pitch (elements); 464 B row, 16B-aligned
#define XPITCH 72    // x-stage row pitch (elems); 144 B row, 16B-aligned, bank-optimal
#define WIMG_ELEMS (7 * 4 * 2 * 64 * 8)   // 28672 ushorts = 57344 B
#define WS_NEEDED ((size_t)WIMG_ELEMS * 2)

typedef short v8s __attribute__((ext_vector_type(8)));
typedef float v4f __attribute__((ext_vector_type(4)));

__device__ __forceinline__ unsigned bf16_rne(float f) {
  unsigned u = __float_as_uint(f);
  return (u + 0x7fffu + ((u >> 16) & 1u)) >> 16;
}

// ============ prep: W -> bf16 hi/lo fragment-order image ============
// idx = (((kt*4+nt)*2+hl)*64 + lane)*8 + i  -> coalesced 1KB frag loads
__global__ void prep_wimg(const float* __restrict__ cw, unsigned short* __restrict__ wimg) {
  int idx = blockIdx.x * 256 + threadIdx.x;
  if (idx >= WIMG_ELEMS) return;
  int i    = idx & 7;
  int lane = (idx >> 3) & 63;
  int hl   = (idx >> 9) & 1;
  int nt   = (idx >> 10) & 3;
  int kt   = idx >> 12;
  int k  = kt * 32 + (lane >> 4) * 8 + i;
  int ch = nt * 16 + (lane & 15);
  float f = (k < NROIS) ? cw[k * HID + ch] : 0.f;
  unsigned hi = bf16_rne(f);
  float lo = f - __uint_as_float(hi << 16);
  wimg[idx] = hl ? (unsigned short)(__float_as_uint(lo) >> 16) : (unsigned short)hi;
}

// ============ fused kernel: graph per block ============
// LDS: max(57600, 77952) + 800 + 800 + 256 = 79808 B -> 2 blocks/CU (16 waves)
struct __align__(16) SmemU {
  union {
    struct {                                  // GEMM1 phase: staged x K-tile
      unsigned short xhi[NPG * XPITCH];       // 28800 B
      unsigned short xlo[NPG * XPITCH];       // 28800 B
    } g1;
    struct {                                  // GEMM2 phase
      unsigned char adj[208 * APITCH];        // 48256 B, (A+I) counts as bytes
      unsigned short hpTl[HID * HPITCH];      // 29696 B, bf16 dinv[src]*h[src][ch]
    } g2;
  } u;
  float dinv[NPG];
  int cnt[NPG];
  int pool[HID];
};

__device__ __forceinline__ void stage_x(SmemU& s, const float* __restrict__ x,
                                        int base, int tk, int tid) {
  const int c0 = tk * 64;
  #pragma unroll
  for (int r = 0; r < 7; ++r) {
    int idx = tid + r * 512;
    if (idx < NPG * 16) {                 // 200 rows x 16 float4
      int node = idx >> 4;
      int f4 = idx & 15;
      int col = c0 + f4 * 4;
      float ff[4];
      if (col + 4 <= NROIS) {
        const float4 v = *(const float4*)(x + (size_t)(base + node) * NROIS + col);
        ff[0] = v.x; ff[1] = v.y; ff[2] = v.z; ff[3] = v.w;
      } else {
        #pragma unroll
        for (int e = 0; e < 4; ++e)
          ff[e] = (col + e < NROIS) ? x[(size_t)(base + node) * NROIS + col + e] : 0.f;
      }
      unsigned hh[4], ll[4];
      #pragma unroll
      for (int e = 0; e < 4; ++e) {
        unsigned uu = __float_as_uint(ff[e]);
        hh[e] = uu >> 16;                                  // trunc hi
        float lo = ff[e] - __uint_as_float(hh[e] << 16);
        ll[e] = __float_as_uint(lo) >> 16;                 // trunc lo
      }
      uint2 ph = {hh[0] | (hh[1] << 16), hh[2] | (hh[3] << 16)};
      uint2 pl = {ll[0] | (ll[1] << 16), ll[2] | (ll[3] << 16)};
      *(uint2*)&s.u.g1.xhi[node * XPITCH + f4 * 4] = ph;
      *(uint2*)&s.u.g1.xlo[node * XPITCH + f4 * 4] = pl;
    }
  }
}

__global__ __launch_bounds__(512, 4)
void gcn_fused2(const float* __restrict__ x,
                const int* __restrict__ ei,
                const unsigned short* __restrict__ wimg,
                const float* __restrict__ cb,
                const float* __restrict__ lw,
                const float* __restrict__ lb,
                float* __restrict__ out,
                int Etot) {
  __shared__ SmemU s;
  const int g = blockIdx.x;
  const int tid = threadIdx.x;
  const int base = g * NPG;
  const int ebase = g * EPG;
  const int lane = tid & 63;
  const int w = __builtin_amdgcn_readfirstlane(tid >> 6);  // 0..7
  const int ml = tid & 15;
  const int q  = (tid >> 4) & 3;

  // ---- phase 0: zero cnt/pool ----
  if (tid < NPG) s.cnt[tid] = 0;
  if (tid < HID) s.pool[tid] = 0;   // relu >= 0 -> 0 is identity for max
  __syncthreads();

  // ---- phase A: edges -> regs + degree count; stage x tile 0 ----
  int esrc[7], edst[7];
  #pragma unroll
  for (int r = 0; r < 7; ++r) {
    int e = tid + r * 512;
    esrc[r] = -1; edst[r] = 0;
    if (e < EPG) {
      esrc[r] = ei[ebase + e] - base;
      edst[r] = ei[Etot + ebase + e] - base;
      atomicAdd(&s.cnt[edst[r]], 1);
    }
  }
  stage_x(s, x, base, 0, tid);
  __syncthreads();

  // ---- phase B: dinv (consumed only after later barriers) ----
  if (tid < NPG) s.dinv[tid] = rsqrtf((float)(s.cnt[tid] + 1));

  // ---- phase C: GEMM1  H = X @ W  (A = W from wimg, B = x from LDS) ----
  int mts[2];
  mts[0] = w;
  mts[1] = (w < 5) ? 8 + w : -1;

  v4f acc[2][4];
  #pragma unroll
  for (int a = 0; a < 2; ++a)
    #pragma unroll
    for (int b = 0; b < 4; ++b)
      acc[a][b] = (v4f){0.f, 0.f, 0.f, 0.f};

  for (int tk = 0; tk < 4; ++tk) {
    #pragma unroll
    for (int half = 0; half < 2; ++half) {
      const int kt = tk * 2 + half;
      if (kt < 7) {
        const int koff = half * 32 + q * 8;
        v8s whi[4], wlo[4];
        #pragma unroll
        for (int nt = 0; nt < 4; ++nt) {
          const unsigned short* pw = wimg + (size_t)(((kt * 4 + nt) * 2) * 64 + lane) * 8;
          whi[nt] = *(const v8s*)pw;                 // coalesced 1KB wave load
          wlo[nt] = *(const v8s*)(pw + 64 * 8);
        }
        #pragma unroll
        for (int mi = 0; mi < 2; ++mi) {
          if (mts[mi] >= 0) {
            const int node = mts[mi] * 16 + ml;
            const int nrd = (node < NPG) ? node : 0;   // clamp: cols >=200 discarded later
            const v8s xh = *(const v8s*)&s.u.g1.xhi[nrd * XPITCH + koff];
            const v8s xl = *(const v8s*)&s.u.g1.xlo[nrd * XPITCH + koff];
            #pragma unroll
            for (int nt = 0; nt < 4; ++nt) {
              acc[mi][nt] = __builtin_amdgcn_mfma_f32_16x16x32_bf16(whi[nt], xl, acc[mi][nt], 0, 0, 0);
              acc[mi][nt] = __builtin_amdgcn_mfma_f32_16x16x32_bf16(wlo[nt], xh, acc[mi][nt], 0, 0, 0);
              acc[mi][nt] = __builtin_amdgcn_mfma_f32_16x16x32_bf16(whi[nt], xh, acc[mi][nt], 0, 0, 0);
            }
          }
        }
      }
    }
    __syncthreads();                     // xbuf reads done
    if (tk < 3) {
      stage_x(s, x, base, tk + 1, tid);
      __syncthreads();
    }
  }

  // ---- phase D: zero adj+hpTl (xbuf dead) ----
  {
    uint4* z = (uint4*)&s.u;
    const uint4 z4 = {0u, 0u, 0u, 0u};
    #pragma unroll
    for (int i = 0; i < 10; ++i) {
      int idx = tid + i * 512;
      if (idx < (208 * APITCH + HID * HPITCH * 2) / 16) z[idx] = z4;
    }
  }
  __syncthreads();

  // ---- phase E: epilogue1 (hpTl = dinv*h, bf16) + adjacency scatter ----
  #pragma unroll
  for (int mi = 0; mi < 2; ++mi) {
    if (mts[mi] >= 0) {
      const int node = mts[mi] * 16 + ml;
      if (node < NPG) {
        const float dv = s.dinv[node];
        #pragma unroll
        for (int nt = 0; nt < 4; ++nt) {
          #pragma unroll
          for (int r = 0; r < 4; ++r) {
            const int ch = nt * 16 + q * 4 + r;
            s.u.g2.hpTl[ch * HPITCH + node] = (unsigned short)bf16_rne(dv * acc[mi][nt][r]);
          }
        }
      }
    }
  }
  {
    unsigned* adjW = (unsigned*)s.u.g2.adj;
    #pragma unroll
    for (int r = 0; r < 7; ++r) {
      if (esrc[r] >= 0) {
        int idx = edst[r] * APITCH + esrc[r];
        atomicAdd(&adjW[idx >> 2], 1u << ((idx & 3) * 8));
      }
    }
    if (tid < NPG) {                      // self-loop diagonal
      int idx = tid * APITCH + tid;
      atomicAdd(&adjW[idx >> 2], 1u << ((idx & 3) * 8));
    }
  }
  __syncthreads();

  // ---- phase F: GEMM2  AGG = (A+I) @ hp  (counts exact in bf16) ----
  {
    v4f acc2[2][4];
    #pragma unroll
    for (int a = 0; a < 2; ++a)
      #pragma unroll
      for (int b = 0; b < 4; ++b)
        acc2[a][b] = (v4f){0.f, 0.f, 0.f, 0.f};

    for (int kt = 0; kt < 7; ++kt) {
      const int k0 = kt * 32 + q * 8;

      v8s bf[4];
      #pragma unroll
      for (int nt = 0; nt < 4; ++nt)
        bf[nt] = *(const v8s*)&s.u.g2.hpTl[(nt * 16 + ml) * HPITCH + k0];

      #pragma unroll
      for (int mi = 0; mi < 2; ++mi) {
        if (mts[mi] >= 0) {
          const int row = mts[mi] * 16 + ml;
          const uint2 dd = *(const uint2*)&s.u.g2.adj[row * APITCH + k0];
          v8s af;
          #pragma unroll
          for (int i = 0; i < 4; ++i) {
            af[i]     = (short)(__float_as_uint((float)((dd.x >> (8 * i)) & 0xffu)) >> 16);
            af[i + 4] = (short)(__float_as_uint((float)((dd.y >> (8 * i)) & 0xffu)) >> 16);
          }
          #pragma unroll
          for (int nt = 0; nt < 4; ++nt)
            acc2[mi][nt] = __builtin_amdgcn_mfma_f32_16x16x32_bf16(af, bf[nt], acc2[mi][nt], 0, 0, 0);
        }
      }
    }

    // epilogue2: relu(dinv[dst]*agg + cb) -> max-pool
    float cbv[4];
    #pragma unroll
    for (int nt = 0; nt < 4; ++nt) cbv[nt] = cb[nt * 16 + ml];
    float mx[4] = {0.f, 0.f, 0.f, 0.f};
    #pragma unroll
    for (int mi = 0; mi < 2; ++mi) {
      if (mts[mi] >= 0) {
        #pragma unroll
        for (int r = 0; r < 4; ++r) {
          const int row = mts[mi] * 16 + q * 4 + r;
          if (row < NPG) {
            const float dv = s.dinv[row];
            #pragma unroll
            for (int nt = 0; nt < 4; ++nt) {
              float v = fmaxf(fmaf(dv, acc2[mi][nt][r], cbv[nt]), 0.f);
              mx[nt] = fmaxf(mx[nt], v);
            }
          }
        }
      }
    }
    #pragma unroll
    for (int nt = 0; nt < 4; ++nt) {
      mx[nt] = fmaxf(mx[nt], __shfl_xor(mx[nt], 16));
      mx[nt] = fmaxf(mx[nt], __shfl_xor(mx[nt], 32));
    }
    if (q == 0 && (lane >> 5) == 0) {
      #pragma unroll
      for (int nt = 0; nt < 4; ++nt)
        atomicMax(&s.pool[nt * 16 + ml], __float_as_int(mx[nt]));
    }
  }
  __syncthreads();

  // ---- phase G: write x_pool and out ----
  if (tid < HID) {
    const float xp = __int_as_float(s.pool[tid]);
    out[NUM_GRAPHS * OUTC + g * HID + tid] = xp;
    float p0 = xp * lw[tid * 2 + 0];
    float p1 = xp * lw[tid * 2 + 1];
    #pragma unroll
    for (int off = 32; off > 0; off >>= 1) {
      p0 += __shfl_down(p0, off);
      p1 += __shfl_down(p1, off);
    }
    if (tid == 0) {
      out[g * OUTC + 0] = p0 + lb[0];
      out[g * OUTC + 1] = p1 + lb[1];
    }
  }
}

// ============ fallback (ws too small): R4 fused kernel, inline W convert ============
struct __align__(16) SmemF {
  unsigned char adj[208 * APITCH];
  unsigned short hpT[HID * HPITCH];
  float dinv[NPG];
  int cnt[NPG];
  int pool[HID];
};

__global__ __launch_bounds__(512, 4)
void gcn_fused_fb(const float* __restrict__ x,
                  const int* __restrict__ ei,
                  const float* __restrict__ cw,
                  const float* __restrict__ cb,
                  const float* __restrict__ lw,
                  const float* __restrict__ lb,
                  float* __restrict__ out,
                  int Etot) {
  __shared__ SmemF s;
  const int g = blockIdx.x;
  const int tid = threadIdx.x;
  const int base = g * NPG;
  const int ebase = g * EPG;
  const int lane = tid & 63;
  const int w = __builtin_amdgcn_readfirstlane(tid >> 6);
  const int ml = tid & 15;
  const int q  = (tid >> 4) & 3;

  {
    uint4* z = (uint4*)&s;
    const uint4 z4 = {0u, 0u, 0u, 0u};
    #pragma unroll
    for (int i = 0; i < 10; ++i) {
      int idx = tid + i * 512;
      if (idx < (208 * APITCH + HID * HPITCH * 2) / 16) z[idx] = z4;
    }
    if (tid < NPG) s.cnt[tid] = 0;
    if (tid < HID) s.pool[tid] = 0;
  }
  __syncthreads();

  int esrc[7], edst[7];
  #pragma unroll
  for (int r = 0; r < 7; ++r) {
    int e = tid + r * 512;
    esrc[r] = -1; edst[r] = 0;
    if (e < EPG) {
      esrc[r] = ei[ebase + e] - base;
      edst[r] = ei[Etot + ebase + e] - base;
      atomicAdd(&s.cnt[edst[r]], 1);
    }
  }
  __syncthreads();

  if (tid < NPG) s.dinv[tid] = rsqrtf((float)(s.cnt[tid] + 1));

  {
    unsigned* adjW = (unsigned*)s.adj;
    #pragma unroll
    for (int r = 0; r < 7; ++r) {
      if (esrc[r] >= 0) {
        int idx = edst[r] * APITCH + esrc[r];
        atomicAdd(&adjW[idx >> 2], 1u << ((idx & 3) * 8));
      }
    }
    if (tid < NPG) {
      int idx = tid * APITCH + tid;
      atomicAdd(&adjW[idx >> 2], 1u << ((idx & 3) * 8));
    }
  }
  __syncthreads();

  {
    int mts[2];
    mts[0] = w;
    mts[1] = (w < 5) ? 8 + w : -1;
    v4f acc[2][4];
    #pragma unroll
    for (int a = 0; a < 2; ++a)
      #pragma unroll
      for (int b = 0; b < 4; ++b)
        acc[a][b] = (v4f){0.f, 0.f, 0.f, 0.f};

    for (int kt = 0; kt < 7; ++kt) {
      const int k0 = kt * 32 + q * 8;
      const bool kok = (k0 < NROIS);
      v8s bhi[4], blo[4];
      #pragma unroll
      for (int nt = 0; nt < 4; ++nt) {
        #pragma unroll
        for (int i = 0; i < 8; ++i) {
          float f = kok ? cw[(k0 + i) * HID + nt * 16 + ml] : 0.f;
          unsigned hb = bf16_rne(f);
          float lo = f - __uint_as_float(hb << 16);
          bhi[nt][i] = (short)hb;
          blo[nt][i] = (short)(__float_as_uint(lo) >> 16);
        }
      }
      #pragma unroll
      for (int mi = 0; mi < 2; ++mi) {
        if (mts[mi] >= 0) {
          const int row = mts[mi] * 16 + ml;
          v8s ahi, alo;
          if (kok && row < NPG) {
            const float* px = x + (size_t)(base + row) * NROIS + k0;
            const float4 f0 = *(const float4*)px;
            const float4 f1 = *(const float4*)(px + 4);
            const float ff[8] = {f0.x, f0.y, f0.z, f0.w, f1.x, f1.y, f1.z, f1.w};
            #pragma unroll
            for (int i = 0; i < 8; ++i) {
              unsigned u = __float_as_uint(ff[i]);
              unsigned hb = u >> 16;
              float lo = ff[i] - __uint_as_float(hb << 16);
              ahi[i] = (short)hb;
              alo[i] = (short)(__float_as_uint(lo) >> 16);
            }
          } else {
            #pragma unroll
            for (int i = 0; i < 8; ++i) { ahi[i] = 0; alo[i] = 0; }
          }
          #pragma unroll
          for (int nt = 0; nt < 4; ++nt) {
            acc[mi][nt] = __builtin_amdgcn_mfma_f32_16x16x32_bf16(ahi, blo[nt], acc[mi][nt], 0, 0, 0);
            acc[mi][nt] = __builtin_amdgcn_mfma_f32_16x16x32_bf16(alo, bhi[nt], acc[mi][nt], 0, 0, 0);
            acc[mi][nt] = __builtin_amdgcn_mfma_f32_16x16x32_bf16(ahi, bhi[nt], acc[mi][nt], 0, 0, 0);
          }
        }
      }
    }
    #pragma unroll
    for (int mi = 0; mi < 2; ++mi) {
      if (mts[mi] >= 0) {
        #pragma unroll
        for (int r = 0; r < 4; ++r) {
          const int row = mts[mi] * 16 + q * 4 + r;
          if (row < NPG) {
            const float dv = s.dinv[row];
            #pragma unroll
            for (int nt = 0; nt < 4; ++nt)
              s.hpT[(nt * 16 + ml) * HPITCH + row] =
                  (unsigned short)bf16_rne(dv * acc[mi][nt][r]);
          }
        }
      }
    }
  }
  __syncthreads();

  {
    int mts[2];
    mts[0] = w;
    mts[1] = (w < 5) ? 8 + w : -1;
    v4f acc2[2][4];
    #pragma unroll
    for (int a = 0; a < 2; ++a)
      #pragma unroll
      for (int b = 0; b < 4; ++b)
        acc2[a][b] = (v4f){0.f, 0.f, 0.f, 0.f};

    for (int kt = 0; kt < 7; ++kt) {
      const int k0 = kt * 32 + q * 8;
      v8s bf[4];
      #pragma unroll
      for (int nt = 0; nt < 4; ++nt)
        bf[nt] = *(const v8s*)&s.hpT[(nt * 16 + ml) * HPITCH + k0];
      #pragma unroll
      for (int mi = 0; mi < 2; ++mi) {
        if (mts[mi] >= 0) {
          const int row = mts[mi] * 16 + ml;
          const uint2 dd = *(const uint2*)&s.adj[row * APITCH + k0];
          v8s af;
          #pragma unroll
          for (int i = 0; i < 4; ++i) {
            af[i]     = (short)(__float_as_uint((float)((dd.x >> (8 * i)) & 0xffu)) >> 16);
            af[i + 4] = (short)(__float_as_uint((float)((dd.y >> (8 * i)) & 0xffu)) >> 16);
          }
          #pragma unroll
          for (int nt = 0; nt < 4; ++nt)
            acc2[mi][nt] = __builtin_amdgcn_mfma_f32_16x16x32_bf16(af, bf[nt], acc2[mi][nt], 0, 0, 0);
        }
      }
    }

    float cbv[4];
    #pragma unroll
    for (int nt = 0; nt < 4; ++nt) cbv[nt] = cb[nt * 16 + ml];
    float mx[4] = {0.f, 0.f, 0.f, 0.f};
    #pragma unroll
    for (int mi = 0; mi < 2; ++mi) {
      if (mts[mi] >= 0) {
        #pragma unroll
        for (int r = 0; r < 4; ++r) {
          const int row = mts[mi] * 16 + q * 4 + r;
          if (row < NPG) {
            const float dv = s.dinv[row];
            #pragma unroll
            for (int nt = 0; nt < 4; ++nt) {
              float v = fmaxf(fmaf(dv, acc2[mi][nt][r], cbv[nt]), 0.f);
              mx[nt] = fmaxf(mx[nt], v);
            }
          }
        }
      }
    }
    #pragma unroll
    for (int nt = 0; nt < 4; ++nt) {
      mx[nt] = fmaxf(mx[nt], __shfl_xor(mx[nt], 16));
      mx[nt] = fmaxf(mx[nt], __shfl_xor(mx[nt], 32));
    }
    if (q == 0 && (lane >> 5) == 0) {
      #pragma unroll
      for (int nt = 0; nt < 4; ++nt)
        atomicMax(&s.pool[nt * 16 + ml], __float_as_int(mx[nt]));
    }
  }
  __syncthreads();

  if (tid < HID) {
    const float xp = __int_as_float(s.pool[tid]);
    out[NUM_GRAPHS * OUTC + g * HID + tid] = xp;
    float p0 = xp * lw[tid * 2 + 0];
    float p1 = xp * lw[tid * 2 + 1];
    #pragma unroll
    for (int off = 32; off > 0; off >>= 1) {
      p0 += __shfl_down(p0, off);
      p1 += __shfl_down(p1, off);
    }
    if (tid == 0) {
      out[g * OUTC + 0] = p0 + lb[0];
      out[g * OUTC + 1] = p1 + lb[1];
    }
  }
}

extern "C" void kernel_launch(void* const* d_in, const int* in_sizes, int n_in,
                              void* d_out, int out_size, void* d_ws, size_t ws_size,
                              hipStream_t stream) {
  const float* x  = (const float*)d_in[0];
  const int*   ei = (const int*)d_in[1];
  // d_in[2] = batch (node/200 by construction; unused)
  const float* cw = (const float*)d_in[3];
  const float* cb = (const float*)d_in[4];
  const float* lw = (const float*)d_in[5];
  const float* lb = (const float*)d_in[6];
  const int Etot = in_sizes[1] / 2;

  if (ws_size >= WS_NEEDED) {
    unsigned short* wimg = (unsigned short*)d_ws;
    prep_wimg<<<(WIMG_ELEMS + 255) / 256, 256, 0, stream>>>(cw, wimg);
    gcn_fused2<<<NUM_GRAPHS, 512, 0, stream>>>(x, ei, wimg, cb, lw, lb,
                                               (float*)d_out, Etot);
  } else {
    gcn_fused_fb<<<NUM_GRAPHS, 512, 0, stream>>>(x, ei, cw, cb, lw, lb,
                                                 (float*)d_out, Etot);
  }
}

// Round 8
// 151.381 us; speedup vs baseline: 1.1087x; 1.0204x over previous
//
#include <hip/hip_runtime.h>

#define NUM_GRAPHS 512
#define NPG 200      // nodes per graph
#define EPG 3200     // edges per graph
#define NROIS 200    // input feature dim
#define HID 64
#define OUTC 2
#define APITCH 232   // adjacency row pitch (bytes) = 58 dw
#define HPITCH 232   // hpTl row pitch (elements)
#define XPITCH 40    // x-stage row pitch (elems); 80 B, 16B-aligned
#define WIMG_ELEMS (7 * 4 * 2 * 64 * 8)   // 28672 ushorts
#define WS_NEEDED ((size_t)WIMG_ELEMS * 2)

typedef short v8s __attribute__((ext_vector_type(8)));
typedef float v4f __attribute__((ext_vector_type(4)));

__device__ __forceinline__ unsigned bf16_rne(float f) {
  unsigned u = __float_as_uint(f);
  return (u + 0x7fffu + ((u >> 16) & 1u)) >> 16;
}

// ============ prep: W -> bf16 hi/lo fragment-order image ============
__global__ void prep_wimg(const float* __restrict__ cw, unsigned short* __restrict__ wimg) {
  int idx = blockIdx.x * 256 + threadIdx.x;
  if (idx >= WIMG_ELEMS) return;
  int i    = idx & 7;
  int lane = (idx >> 3) & 63;
  int hl   = (idx >> 9) & 1;
  int nt   = (idx >> 10) & 3;
  int kt   = idx >> 12;
  int k  = kt * 32 + (lane >> 4) * 8 + i;
  int ch = nt * 16 + (lane & 15);
  float f = (k < NROIS) ? cw[k * HID + ch] : 0.f;
  unsigned hi = bf16_rne(f);
  float lo = f - __uint_as_float(hi << 16);
  wimg[idx] = hl ? (unsigned short)(__float_as_uint(lo) >> 16) : (unsigned short)hi;
}

// ============ fused kernel ============
// LDS: 48256 (adj, persistent) + 32000 (xbuf K=32 | hpTl) + 800 + 256 = 81312 B
// -> exactly 2 blocks/CU (<= 81920 each)
struct __align__(16) SmemU {
  unsigned char adj[208 * APITCH];                 // (A+I) counts as bytes
  union {
    struct { unsigned short xhi[NPG * XPITCH];
             unsigned short xlo[NPG * XPITCH]; } g1;   // 32000 B (K=32 tile)
    unsigned short hpTl[HID * HPITCH];             // 29696 B
  } u;
  float dinv[NPG];
  int pool[HID];
};

__device__ __forceinline__ void xload(float4* xf, const float* __restrict__ x,
                                      int base, int c0, int tid) {
  #pragma unroll
  for (int r = 0; r < 4; ++r) {
    int idx = tid + r * 512;
    int node = idx >> 3, f4 = idx & 7;
    int col = c0 + f4 * 4;
    if (idx < 1600 && col + 4 <= NROIS)
      xf[r] = *(const float4*)(x + (size_t)(base + node) * NROIS + col);
    else
      xf[r] = make_float4(0.f, 0.f, 0.f, 0.f);
  }
}

__device__ __forceinline__ void xwrite(SmemU& s, const float4* xf, int tid) {
  #pragma unroll
  for (int r = 0; r < 4; ++r) {
    int idx = tid + r * 512;
    if (idx < 1600) {
      int node = idx >> 3, f4 = idx & 7;
      const float ff[4] = {xf[r].x, xf[r].y, xf[r].z, xf[r].w};
      unsigned hh[4], ll[4];
      #pragma unroll
      for (int e = 0; e < 4; ++e) {
        unsigned uu = __float_as_uint(ff[e]);
        hh[e] = uu >> 16;                                  // trunc hi
        float lo = ff[e] - __uint_as_float(hh[e] << 16);
        ll[e] = __float_as_uint(lo) >> 16;                 // trunc lo
      }
      uint2 ph = {hh[0] | (hh[1] << 16), hh[2] | (hh[3] << 16)};
      uint2 pl = {ll[0] | (ll[1] << 16), ll[2] | (ll[3] << 16)};
      *(uint2*)&s.u.g1.xhi[node * XPITCH + f4 * 4] = ph;
      *(uint2*)&s.u.g1.xlo[node * XPITCH + f4 * 4] = pl;
    }
  }
}

__global__ __launch_bounds__(512, 4)
void gcn_fused3(const float* __restrict__ x,
                const int* __restrict__ ei,
                const unsigned short* __restrict__ wimg,
                const float* __restrict__ cb,
                const float* __restrict__ lw,
                const float* __restrict__ lb,
                float* __restrict__ out,
                int Etot) {
  __shared__ SmemU s;
  const int g = blockIdx.x;
  const int tid = threadIdx.x;
  const int base = g * NPG;
  const int ebase = g * EPG;
  const int lane = tid & 63;
  const int w = __builtin_amdgcn_readfirstlane(tid >> 6);  // 0..7
  const int ml = tid & 15;
  const int q  = (tid >> 4) & 3;

  // ---- startup: issue stage-tile0 + edge loads, zero adj+pool ----
  float4 xf[4];
  xload(xf, x, base, 0, tid);
  int esrc[7], edst[7];
  #pragma unroll
  for (int r = 0; r < 7; ++r) {
    int e = tid + r * 512;
    esrc[r] = -1; edst[r] = 0;
    if (e < EPG) {
      esrc[r] = ei[ebase + e] - base;
      edst[r] = ei[Etot + ebase + e] - base;
    }
  }
  {
    uint4* z = (uint4*)s.adj;
    const uint4 z4 = {0u, 0u, 0u, 0u};
    #pragma unroll
    for (int i = 0; i < 6; ++i) {
      int idx = tid + i * 512;
      if (idx < (208 * APITCH) / 16) z[idx] = z4;
    }
    if (tid < HID) s.pool[tid] = 0;   // relu >= 0 -> 0 is identity for max
  }
  __syncthreads();

  // ---- scatter (A+I) counts (dup-safe packed byte atomics) + write xbuf tile0 ----
  {
    unsigned* adjW = (unsigned*)s.adj;
    #pragma unroll
    for (int r = 0; r < 7; ++r) {
      if (esrc[r] >= 0) {
        int idx = edst[r] * APITCH + esrc[r];
        atomicAdd(&adjW[idx >> 2], 1u << ((idx & 3) * 8));
      }
    }
    if (tid < NPG) {                      // self-loop diagonal
      int idx = tid * APITCH + tid;
      atomicAdd(&adjW[idx >> 2], 1u << ((idx & 3) * 8));
    }
  }
  xwrite(s, xf, tid);
  __syncthreads();

  // ---- GEMM1: H = X @ W (W frags from wimg; x from LDS; reg-prefetch next tile) ----
  int mts[2];
  mts[0] = w;
  mts[1] = (w < 5) ? 8 + w : -1;

  v4f acc[2][4];
  #pragma unroll
  for (int a = 0; a < 2; ++a)
    #pragma unroll
    for (int b = 0; b < 4; ++b)
      acc[a][b] = (v4f){0.f, 0.f, 0.f, 0.f};

  for (int kt = 0; kt < 7; ++kt) {
    float4 xfn[4];
    if (kt < 6) xload(xfn, x, base, (kt + 1) * 32, tid);   // in flight during MFMAs

    v8s whi[4], wlo[4];
    #pragma unroll
    for (int nt = 0; nt < 4; ++nt) {
      const unsigned short* pw = wimg + (size_t)(((kt * 4 + nt) * 2) * 64 + lane) * 8;
      whi[nt] = *(const v8s*)pw;                 // coalesced 1KB wave load
      wlo[nt] = *(const v8s*)(pw + 64 * 8);
    }
    #pragma unroll
    for (int mi = 0; mi < 2; ++mi) {
      if (mts[mi] >= 0) {
        const int node = mts[mi] * 16 + ml;
        const int nrd = (node < NPG) ? node : 0;   // clamp; junk rows discarded later
        const v8s xh = *(const v8s*)&s.u.g1.xhi[nrd * XPITCH + q * 8];
        const v8s xl = *(const v8s*)&s.u.g1.xlo[nrd * XPITCH + q * 8];
        #pragma unroll
        for (int nt = 0; nt < 4; ++nt) {
          acc[mi][nt] = __builtin_amdgcn_mfma_f32_16x16x32_bf16(whi[nt], xl, acc[mi][nt], 0, 0, 0);
          acc[mi][nt] = __builtin_amdgcn_mfma_f32_16x16x32_bf16(wlo[nt], xh, acc[mi][nt], 0, 0, 0);
          acc[mi][nt] = __builtin_amdgcn_mfma_f32_16x16x32_bf16(whi[nt], xh, acc[mi][nt], 0, 0, 0);
        }
      }
    }
    __syncthreads();                     // xbuf reads done
    if (kt < 6) {
      xwrite(s, xfn, tid);
      __syncthreads();
    }
  }

  // ---- degree = adjacency row-sum (includes self-loop) -> dinv; zero hpTl pad cols ----
  if (tid < NPG) {
    const unsigned* ap = (const unsigned*)s.adj + tid * (APITCH / 4);
    unsigned ssum = 0;
    #pragma unroll 2
    for (int j = 0; j < APITCH / 4; ++j)
      ssum += (ap[j] * 0x01010101u) >> 24;       // exact: per-row degree << 255
    s.dinv[tid] = rsqrtf((float)ssum);
  }
  {
    // hpTl cols [200,232) must be finite (adj there is 0, but 0*NaN = NaN)
    int ch = tid >> 3, grp = tid & 7;
    *(uint2*)&s.u.hpTl[ch * HPITCH + 200 + grp * 4] = (uint2){0u, 0u};
  }
  __syncthreads();

  // ---- epilogue1: hpTl[ch][node] = bf16(dinv[node] * h) (overlays xbuf) ----
  #pragma unroll
  for (int mi = 0; mi < 2; ++mi) {
    if (mts[mi] >= 0) {
      const int node = mts[mi] * 16 + ml;
      if (node < NPG) {
        const float dv = s.dinv[node];
        #pragma unroll
        for (int nt = 0; nt < 4; ++nt) {
          #pragma unroll
          for (int r = 0; r < 4; ++r) {
            const int ch = nt * 16 + q * 4 + r;
            s.u.hpTl[ch * HPITCH + node] = (unsigned short)bf16_rne(dv * acc[mi][nt][r]);
          }
        }
      }
    }
  }
  __syncthreads();

  // ---- GEMM2: AGG = (A+I) @ hp (counts exact in bf16) ----
  {
    v4f acc2[2][4];
    #pragma unroll
    for (int a = 0; a < 2; ++a)
      #pragma unroll
      for (int b = 0; b < 4; ++b)
        acc2[a][b] = (v4f){0.f, 0.f, 0.f, 0.f};

    for (int kt = 0; kt < 7; ++kt) {
      const int k0 = kt * 32 + q * 8;

      v8s bf[4];
      #pragma unroll
      for (int nt = 0; nt < 4; ++nt)
        bf[nt] = *(const v8s*)&s.u.hpTl[(nt * 16 + ml) * HPITCH + k0];

      #pragma unroll
      for (int mi = 0; mi < 2; ++mi) {
        if (mts[mi] >= 0) {
          const int row = mts[mi] * 16 + ml;
          const uint2 dd = *(const uint2*)&s.adj[row * APITCH + k0];
          v8s af;
          #pragma unroll
          for (int i = 0; i < 4; ++i) {
            af[i]     = (short)(__float_as_uint((float)((dd.x >> (8 * i)) & 0xffu)) >> 16);
            af[i + 4] = (short)(__float_as_uint((float)((dd.y >> (8 * i)) & 0xffu)) >> 16);
          }
          #pragma unroll
          for (int nt = 0; nt < 4; ++nt)
            acc2[mi][nt] = __builtin_amdgcn_mfma_f32_16x16x32_bf16(af, bf[nt], acc2[mi][nt], 0, 0, 0);
        }
      }
    }

    // epilogue2: relu(dinv[dst]*agg + cb) -> max-pool
    float cbv[4];
    #pragma unroll
    for (int nt = 0; nt < 4; ++nt) cbv[nt] = cb[nt * 16 + ml];
    float mx[4] = {0.f, 0.f, 0.f, 0.f};
    #pragma unroll
    for (int mi = 0; mi < 2; ++mi) {
      if (mts[mi] >= 0) {
        #pragma unroll
        for (int r = 0; r < 4; ++r) {
          const int row = mts[mi] * 16 + q * 4 + r;
          if (row < NPG) {
            const float dv = s.dinv[row];
            #pragma unroll
            for (int nt = 0; nt < 4; ++nt) {
              float v = fmaxf(fmaf(dv, acc2[mi][nt][r], cbv[nt]), 0.f);
              mx[nt] = fmaxf(mx[nt], v);
            }
          }
        }
      }
    }
    #pragma unroll
    for (int nt = 0; nt < 4; ++nt) {
      mx[nt] = fmaxf(mx[nt], __shfl_xor(mx[nt], 16));
      mx[nt] = fmaxf(mx[nt], __shfl_xor(mx[nt], 32));
    }
    if (q == 0 && (lane >> 5) == 0) {
      #pragma unroll
      for (int nt = 0; nt < 4; ++nt)
        atomicMax(&s.pool[nt * 16 + ml], __float_as_int(mx[nt]));
    }
  }
  __syncthreads();

  // ---- write x_pool and out ----
  if (tid < HID) {
    const float xp = __int_as_float(s.pool[tid]);
    out[NUM_GRAPHS * OUTC + g * HID + tid] = xp;
    float p0 = xp * lw[tid * 2 + 0];
    float p1 = xp * lw[tid * 2 + 1];
    #pragma unroll
    for (int off = 32; off > 0; off >>= 1) {
      p0 += __shfl_down(p0, off);
      p1 += __shfl_down(p1, off);
    }
    if (tid == 0) {
      out[g * OUTC + 0] = p0 + lb[0];
      out[g * OUTC + 1] = p1 + lb[1];
    }
  }
}

// ============ fallback (ws too small): R7 fused kernel, inline W convert ============
struct __align__(16) SmemF {
  unsigned char adj[208 * APITCH];
  unsigned short hpT[HID * HPITCH];
  float dinv[NPG];
  int cnt[NPG];
  int pool[HID];
};

__global__ __launch_bounds__(512, 4)
void gcn_fused_fb(const float* __restrict__ x,
                  const int* __restrict__ ei,
                  const float* __restrict__ cw,
                  const float* __restrict__ cb,
                  const float* __restrict__ lw,
                  const float* __restrict__ lb,
                  float* __restrict__ out,
                  int Etot) {
  __shared__ SmemF s;
  const int g = blockIdx.x;
  const int tid = threadIdx.x;
  const int base = g * NPG;
  const int ebase = g * EPG;
  const int lane = tid & 63;
  const int w = __builtin_amdgcn_readfirstlane(tid >> 6);
  const int ml = tid & 15;
  const int q  = (tid >> 4) & 3;

  {
    uint4* z = (uint4*)&s;
    const uint4 z4 = {0u, 0u, 0u, 0u};
    #pragma unroll
    for (int i = 0; i < 10; ++i) {
      int idx = tid + i * 512;
      if (idx < (208 * APITCH + HID * HPITCH * 2) / 16) z[idx] = z4;
    }
    if (tid < NPG) s.cnt[tid] = 0;
    if (tid < HID) s.pool[tid] = 0;
  }
  __syncthreads();

  int esrc[7], edst[7];
  #pragma unroll
  for (int r = 0; r < 7; ++r) {
    int e = tid + r * 512;
    esrc[r] = -1; edst[r] = 0;
    if (e < EPG) {
      esrc[r] = ei[ebase + e] - base;
      edst[r] = ei[Etot + ebase + e] - base;
      atomicAdd(&s.cnt[edst[r]], 1);
    }
  }
  __syncthreads();

  if (tid < NPG) s.dinv[tid] = rsqrtf((float)(s.cnt[tid] + 1));

  {
    unsigned* adjW = (unsigned*)s.adj;
    #pragma unroll
    for (int r = 0; r < 7; ++r) {
      if (esrc[r] >= 0) {
        int idx = edst[r] * APITCH + esrc[r];
        atomicAdd(&adjW[idx >> 2], 1u << ((idx & 3) * 8));
      }
    }
    if (tid < NPG) {
      int idx = tid * APITCH + tid;
      atomicAdd(&adjW[idx >> 2], 1u << ((idx & 3) * 8));
    }
  }
  __syncthreads();

  {
    int mts[2];
    mts[0] = w;
    mts[1] = (w < 5) ? 8 + w : -1;
    v4f acc[2][4];
    #pragma unroll
    for (int a = 0; a < 2; ++a)
      #pragma unroll
      for (int b = 0; b < 4; ++b)
        acc[a][b] = (v4f){0.f, 0.f, 0.f, 0.f};

    for (int kt = 0; kt < 7; ++kt) {
      const int k0 = kt * 32 + q * 8;
      const bool kok = (k0 < NROIS);
      v8s bhi[4], blo[4];
      #pragma unroll
      for (int nt = 0; nt < 4; ++nt) {
        #pragma unroll
        for (int i = 0; i < 8; ++i) {
          float f = kok ? cw[(k0 + i) * HID + nt * 16 + ml] : 0.f;
          unsigned hb = bf16_rne(f);
          float lo = f - __uint_as_float(hb << 16);
          bhi[nt][i] = (short)hb;
          blo[nt][i] = (short)(__float_as_uint(lo) >> 16);
        }
      }
      #pragma unroll
      for (int mi = 0; mi < 2; ++mi) {
        if (mts[mi] >= 0) {
          const int row = mts[mi] * 16 + ml;
          v8s ahi, alo;
          if (kok && row < NPG) {
            const float* px = x + (size_t)(base + row) * NROIS + k0;
            const float4 f0 = *(const float4*)px;
            const float4 f1 = *(const float4*)(px + 4);
            const float ff[8] = {f0.x, f0.y, f0.z, f0.w, f1.x, f1.y, f1.z, f1.w};
            #pragma unroll
            for (int i = 0; i < 8; ++i) {
              unsigned u = __float_as_uint(ff[i]);
              unsigned hb = u >> 16;
              float lo = ff[i] - __uint_as_float(hb << 16);
              ahi[i] = (short)hb;
              alo[i] = (short)(__float_as_uint(lo) >> 16);
            }
          } else {
            #pragma unroll
            for (int i = 0; i < 8; ++i) { ahi[i] = 0; alo[i] = 0; }
          }
          #pragma unroll
          for (int nt = 0; nt < 4; ++nt) {
            acc[mi][nt] = __builtin_amdgcn_mfma_f32_16x16x32_bf16(ahi, blo[nt], acc[mi][nt], 0, 0, 0);
            acc[mi][nt] = __builtin_amdgcn_mfma_f32_16x16x32_bf16(alo, bhi[nt], acc[mi][nt], 0, 0, 0);
            acc[mi][nt] = __builtin_amdgcn_mfma_f32_16x16x32_bf16(ahi, bhi[nt], acc[mi][nt], 0, 0, 0);
          }
        }
      }
    }
    #pragma unroll
    for (int mi = 0; mi < 2; ++mi) {
      if (mts[mi] >= 0) {
        #pragma unroll
        for (int r = 0; r < 4; ++r) {
          const int row = mts[mi] * 16 + q * 4 + r;
          if (row < NPG) {
            const float dv = s.dinv[row];
            #pragma unroll
            for (int nt = 0; nt < 4; ++nt)
              s.hpT[(nt * 16 + ml) * HPITCH + row] =
                  (unsigned short)bf16_rne(dv * acc[mi][nt][r]);
          }
        }
      }
    }
  }
  __syncthreads();

  {
    int mts[2];
    mts[0] = w;
    mts[1] = (w < 5) ? 8 + w : -1;
    v4f acc2[2][4];
    #pragma unroll
    for (int a = 0; a < 2; ++a)
      #pragma unroll
      for (int b = 0; b < 4; ++b)
        acc2[a][b] = (v4f){0.f, 0.f, 0.f, 0.f};

    for (int kt = 0; kt < 7; ++kt) {
      const int k0 = kt * 32 + q * 8;
      v8s bf[4];
      #pragma unroll
      for (int nt = 0; nt < 4; ++nt)
        bf[nt] = *(const v8s*)&s.hpT[(nt * 16 + ml) * HPITCH + k0];
      #pragma unroll
      for (int mi = 0; mi < 2; ++mi) {
        if (mts[mi] >= 0) {
          const int row = mts[mi] * 16 + ml;
          const uint2 dd = *(const uint2*)&s.adj[row * APITCH + k0];
          v8s af;
          #pragma unroll
          for (int i = 0; i < 4; ++i) {
            af[i]     = (short)(__float_as_uint((float)((dd.x >> (8 * i)) & 0xffu)) >> 16);
            af[i + 4] = (short)(__float_as_uint((float)((dd.y >> (8 * i)) & 0xffu)) >> 16);
          }
          #pragma unroll
          for (int nt = 0; nt < 4; ++nt)
            acc2[mi][nt] = __builtin_amdgcn_mfma_f32_16x16x32_bf16(af, bf[nt], acc2[mi][nt], 0, 0, 0);
        }
      }
    }

    float cbv[4];
    #pragma unroll
    for (int nt = 0; nt < 4; ++nt) cbv[nt] = cb[nt * 16 + ml];
    float mx[4] = {0.f, 0.f, 0.f, 0.f};
    #pragma unroll
    for (int mi = 0; mi < 2; ++mi) {
      if (mts[mi] >= 0) {
        #pragma unroll
        for (int r = 0; r < 4; ++r) {
          const int row = mts[mi] * 16 + q * 4 + r;
          if (row < NPG) {
            const float dv = s.dinv[row];
            #pragma unroll
            for (int nt = 0; nt < 4; ++nt) {
              float v = fmaxf(fmaf(dv, acc2[mi][nt][r], cbv[nt]), 0.f);
              mx[nt] = fmaxf(mx[nt], v);
            }
          }
        }
      }
    }
    #pragma unroll
    for (int nt = 0; nt < 4; ++nt) {
      mx[nt] = fmaxf(mx[nt], __shfl_xor(mx[nt], 16));
      mx[nt] = fmaxf(mx[nt], __shfl_xor(mx[nt], 32));
    }
    if (q == 0 && (lane >> 5) == 0) {
      #pragma unroll
      for (int nt = 0; nt < 4; ++nt)
        atomicMax(&s.pool[nt * 16 + ml], __float_as_int(mx[nt]));
    }
  }
  __syncthreads();

  if (tid < HID) {
    const float xp = __int_as_float(s.pool[tid]);
    out[NUM_GRAPHS * OUTC + g * HID + tid] = xp;
    float p0 = xp * lw[tid * 2 + 0];
    float p1 = xp * lw[tid * 2 + 1];
    #pragma unroll
    for (int off = 32; off > 0; off >>= 1) {
      p0 += __shfl_down(p0, off);
      p1 += __shfl_down(p1, off);
    }
    if (tid == 0) {
      out[g * OUTC + 0] = p0 + lb[0];
      out[g * OUTC + 1] = p1 + lb[1];
    }
  }
}

extern "C" void kernel_launch(void* const* d_in, const int* in_sizes, int n_in,
                              void* d_out, int out_size, void* d_ws, size_t ws_size,
                              hipStream_t stream) {
  const float* x  = (const float*)d_in[0];
  const int*   ei = (const int*)d_in[1];
  // d_in[2] = batch (node/200 by construction; unused)
  const float* cw = (const float*)d_in[3];
  const float* cb = (const float*)d_in[4];
  const float* lw = (const float*)d_in[5];
  const float* lb = (const float*)d_in[6];
  const int Etot = in_sizes[1] / 2;

  if (ws_size >= WS_NEEDED) {
    unsigned short* wimg = (unsigned short*)d_ws;
    prep_wimg<<<(WIMG_ELEMS + 255) / 256, 256, 0, stream>>>(cw, wimg);
    gcn_fused3<<<NUM_GRAPHS, 512, 0, stream>>>(x, ei, wimg, cb, lw, lb,
                                               (float*)d_out, Etot);
  } else {
    gcn_fused_fb<<<NUM_GRAPHS, 512, 0, stream>>>(x, ei, cw, cb, lw, lb,
                                                 (float*)d_out, Etot);
  }
}

// Round 9
// 150.104 us; speedup vs baseline: 1.1182x; 1.0085x over previous
//
#include <hip/hip_runtime.h>

#define NUM_GRAPHS 512
#define NPG 200      // nodes per graph
#define EPG 3200     // edges per graph
#define NROIS 200    // input feature dim
#define HID 64
#define OUTC 2
#define APITCH 232   // adjacency row pitch (bytes) = 58 dw
#define HPITCH 232   // hpTl row pitch (elements)
#define XPITCH 40    // x-stage row pitch (elems); 80 B, 16B-aligned
#define WIMG_ELEMS (7 * 4 * 2 * 64 * 8)   // 28672 ushorts (W hi/lo frag image)
#define WS_NEEDED ((size_t)WIMG_ELEMS * 2)

typedef short v8s __attribute__((ext_vector_type(8)));
typedef float v4f __attribute__((ext_vector_type(4)));

__device__ __forceinline__ unsigned bf16_rne(float f) {
  unsigned u = __float_as_uint(f);
  return (u + 0x7fffu + ((u >> 16) & 1u)) >> 16;
}

// ============ prep: W -> bf16 hi/lo fragment-order image ============
__global__ void prep_wimg(const float* __restrict__ cw, unsigned short* __restrict__ wimg) {
  int idx = blockIdx.x * 256 + threadIdx.x;
  if (idx >= WIMG_ELEMS) return;
  int i    = idx & 7;
  int lane = (idx >> 3) & 63;
  int hl   = (idx >> 9) & 1;
  int nt   = (idx >> 10) & 3;
  int kt   = idx >> 12;
  int k  = kt * 32 + (lane >> 4) * 8 + i;
  int ch = nt * 16 + (lane & 15);
  float f = (k < NROIS) ? cw[k * HID + ch] : 0.f;
  unsigned hi = bf16_rne(f);
  float lo = f - __uint_as_float(hi << 16);
  wimg[idx] = hl ? (unsigned short)(__float_as_uint(lo) >> 16) : (unsigned short)hi;
}

// ============ fused kernel ============
// LDS: 48256 (adj) + 32000 (2x xbuf | hpTl) + 800 + 256 = 81312 B -> 2 blocks/CU
struct __align__(16) SmemU {
  unsigned char adj[208 * APITCH];                 // (A+I) counts as bytes
  union {
    unsigned short xb[2][NPG * XPITCH];            // double-buffered x (RNE bf16)
    unsigned short hpTl[HID * HPITCH];             // bf16 dinv[src]*h[src][ch]
  } u;
  float dinv[NPG];
  int pool[HID];
};

__device__ __forceinline__ void xload(float4* xf, const float* __restrict__ x,
                                      int base, int c0, int tid) {
  #pragma unroll
  for (int r = 0; r < 4; ++r) {
    int idx = tid + r * 512;
    int node = idx >> 3, f4 = idx & 7;
    int col = c0 + f4 * 4;
    if (idx < 1600 && col + 4 <= NROIS)
      xf[r] = *(const float4*)(x + (size_t)(base + node) * NROIS + col);
    else
      xf[r] = make_float4(0.f, 0.f, 0.f, 0.f);
  }
}

__device__ __forceinline__ void xwrite(SmemU& s, int buf, const float4* xf, int tid) {
  #pragma unroll
  for (int r = 0; r < 4; ++r) {
    int idx = tid + r * 512;
    if (idx < 1600) {
      int node = idx >> 3, f4 = idx & 7;
      unsigned b0 = bf16_rne(xf[r].x), b1 = bf16_rne(xf[r].y);
      unsigned b2 = bf16_rne(xf[r].z), b3 = bf16_rne(xf[r].w);
      uint2 p = {b0 | (b1 << 16), b2 | (b3 << 16)};
      *(uint2*)&s.u.xb[buf][node * XPITCH + f4 * 4] = p;
    }
  }
}

__global__ __launch_bounds__(512, 4)
void gcn_fused4(const float* __restrict__ x,
                const int* __restrict__ ei,
                const unsigned short* __restrict__ wimg,
                const float* __restrict__ cb,
                const float* __restrict__ lw,
                const float* __restrict__ lb,
                float* __restrict__ out,
                int Etot) {
  __shared__ SmemU s;
  const int g = blockIdx.x;
  const int tid = threadIdx.x;
  const int base = g * NPG;
  const int ebase = g * EPG;
  const int lane = tid & 63;
  const int w = __builtin_amdgcn_readfirstlane(tid >> 6);  // 0..7
  const int ml = tid & 15;
  const int q  = (tid >> 4) & 3;

  // ---- startup: issue x-tile0 + edge loads; zero adj + pool ----
  float4 xf[4];
  xload(xf, x, base, 0, tid);
  int esrc[7], edst[7];
  #pragma unroll
  for (int r = 0; r < 7; ++r) {
    int e = tid + r * 512;
    esrc[r] = -1; edst[r] = 0;
    if (e < EPG) {
      esrc[r] = ei[ebase + e] - base;
      edst[r] = ei[Etot + ebase + e] - base;
    }
  }
  {
    uint4* z = (uint4*)s.adj;
    const uint4 z4 = {0u, 0u, 0u, 0u};
    #pragma unroll
    for (int i = 0; i < 6; ++i) {
      int idx = tid + i * 512;
      if (idx < (208 * APITCH) / 16) z[idx] = z4;
    }
    if (tid < HID) s.pool[tid] = 0;   // relu >= 0 -> 0 is identity for max
  }
  __syncthreads();

  // ---- scatter (A+I) counts (dup-safe packed byte atomics) + write xbuf0 ----
  {
    unsigned* adjW = (unsigned*)s.adj;
    #pragma unroll
    for (int r = 0; r < 7; ++r) {
      if (esrc[r] >= 0) {
        int idx = edst[r] * APITCH + esrc[r];
        atomicAdd(&adjW[idx >> 2], 1u << ((idx & 3) * 8));
      }
    }
    if (tid < NPG) {                      // self-loop diagonal
      int idx = tid * APITCH + tid;
      atomicAdd(&adjW[idx >> 2], 1u << ((idx & 3) * 8));
    }
  }
  xwrite(s, 0, xf, tid);
  __syncthreads();

  // ---- degree = adjacency row-sum -> dinv (overlaps GEMM1; 2 threads/row) ----
  {
    int row = tid >> 1, half = tid & 1;
    if (row < NPG) {
      const unsigned* ap = (const unsigned*)s.adj + row * (APITCH / 4) + half * 29;
      unsigned ssum = 0;
      #pragma unroll 4
      for (int j = 0; j < 29; ++j)
        ssum += (ap[j] * 0x01010101u) >> 24;     // exact byte-sum (counts tiny)
      ssum += __shfl_xor((int)ssum, 1);
      if (half == 0) s.dinv[row] = rsqrtf((float)ssum);
    }
  }

  // ---- GEMM1: H = X @ W  (x single RNE bf16; W hi/lo; double-buffered xbuf) ----
  int mts[2];
  mts[0] = w;
  mts[1] = (w < 5) ? 8 + w : -1;

  v4f acc[2][4];
  #pragma unroll
  for (int a = 0; a < 2; ++a)
    #pragma unroll
    for (int b = 0; b < 4; ++b)
      acc[a][b] = (v4f){0.f, 0.f, 0.f, 0.f};

  for (int kt = 0; kt < 7; ++kt) {
    float4 xfn[4];
    if (kt < 6) xload(xfn, x, base, (kt + 1) * 32, tid);   // in flight during MFMAs

    v8s whi[4], wlo[4];
    #pragma unroll
    for (int nt = 0; nt < 4; ++nt) {
      const unsigned short* pw = wimg + (size_t)(((kt * 4 + nt) * 2) * 64 + lane) * 8;
      whi[nt] = *(const v8s*)pw;                 // coalesced 1KB wave load
      wlo[nt] = *(const v8s*)(pw + 64 * 8);
    }
    #pragma unroll
    for (int mi = 0; mi < 2; ++mi) {
      if (mts[mi] >= 0) {
        const int node = mts[mi] * 16 + ml;
        const int nrd = (node < NPG) ? node : 0;   // clamp; junk rows discarded later
        const v8s xh = *(const v8s*)&s.u.xb[kt & 1][nrd * XPITCH + q * 8];
        #pragma unroll
        for (int nt = 0; nt < 4; ++nt) {
          acc[mi][nt] = __builtin_amdgcn_mfma_f32_16x16x32_bf16(wlo[nt], xh, acc[mi][nt], 0, 0, 0);
          acc[mi][nt] = __builtin_amdgcn_mfma_f32_16x16x32_bf16(whi[nt], xh, acc[mi][nt], 0, 0, 0);
        }
      }
    }
    if (kt < 6) xwrite(s, (kt + 1) & 1, xfn, tid);   // other buffer: no read hazard
    __syncthreads();
  }

  // ---- epilogue1: pad-zero + hpTl[ch][node] = bf16(dinv[node] * h) ----
  {
    // hpTl cols [200,232) must be finite (adj there is 0, but 0*garbage = NaN risk)
    int ch = tid >> 3, grp = tid & 7;
    *(uint2*)&s.u.hpTl[ch * HPITCH + 200 + grp * 4] = (uint2){0u, 0u};
  }
  #pragma unroll
  for (int mi = 0; mi < 2; ++mi) {
    if (mts[mi] >= 0) {
      const int node = mts[mi] * 16 + ml;
      if (node < NPG) {
        const float dv = s.dinv[node];
        #pragma unroll
        for (int nt = 0; nt < 4; ++nt) {
          #pragma unroll
          for (int r = 0; r < 4; ++r) {
            const int ch = nt * 16 + q * 4 + r;
            s.u.hpTl[ch * HPITCH + node] = (unsigned short)bf16_rne(dv * acc[mi][nt][r]);
          }
        }
      }
    }
  }
  __syncthreads();

  // ---- GEMM2: AGG = (A+I) @ hp (counts exact in bf16) ----
  {
    v4f acc2[2][4];
    #pragma unroll
    for (int a = 0; a < 2; ++a)
      #pragma unroll
      for (int b = 0; b < 4; ++b)
        acc2[a][b] = (v4f){0.f, 0.f, 0.f, 0.f};

    for (int kt = 0; kt < 7; ++kt) {
      const int k0 = kt * 32 + q * 8;

      v8s bf[4];
      #pragma unroll
      for (int nt = 0; nt < 4; ++nt)
        bf[nt] = *(const v8s*)&s.u.hpTl[(nt * 16 + ml) * HPITCH + k0];

      #pragma unroll
      for (int mi = 0; mi < 2; ++mi) {
        if (mts[mi] >= 0) {
          const int row = mts[mi] * 16 + ml;
          const uint2 dd = *(const uint2*)&s.adj[row * APITCH + k0];
          v8s af;
          #pragma unroll
          for (int i = 0; i < 4; ++i) {
            af[i]     = (short)(__float_as_uint((float)((dd.x >> (8 * i)) & 0xffu)) >> 16);
            af[i + 4] = (short)(__float_as_uint((float)((dd.y >> (8 * i)) & 0xffu)) >> 16);
          }
          #pragma unroll
          for (int nt = 0; nt < 4; ++nt)
            acc2[mi][nt] = __builtin_amdgcn_mfma_f32_16x16x32_bf16(af, bf[nt], acc2[mi][nt], 0, 0, 0);
        }
      }
    }

    // epilogue2: relu(dinv[dst]*agg + cb) -> max-pool
    float cbv[4];
    #pragma unroll
    for (int nt = 0; nt < 4; ++nt) cbv[nt] = cb[nt * 16 + ml];
    float mx[4] = {0.f, 0.f, 0.f, 0.f};
    #pragma unroll
    for (int mi = 0; mi < 2; ++mi) {
      if (mts[mi] >= 0) {
        #pragma unroll
        for (int r = 0; r < 4; ++r) {
          const int row = mts[mi] * 16 + q * 4 + r;
          if (row < NPG) {
            const float dv = s.dinv[row];
            #pragma unroll
            for (int nt = 0; nt < 4; ++nt) {
              float v = fmaxf(fmaf(dv, acc2[mi][nt][r], cbv[nt]), 0.f);
              mx[nt] = fmaxf(mx[nt], v);
            }
          }
        }
      }
    }
    #pragma unroll
    for (int nt = 0; nt < 4; ++nt) {
      mx[nt] = fmaxf(mx[nt], __shfl_xor(mx[nt], 16));
      mx[nt] = fmaxf(mx[nt], __shfl_xor(mx[nt], 32));
    }
    if (q == 0 && (lane >> 5) == 0) {
      #pragma unroll
      for (int nt = 0; nt < 4; ++nt)
        atomicMax(&s.pool[nt * 16 + ml], __float_as_int(mx[nt]));
    }
  }
  __syncthreads();

  // ---- write x_pool and out ----
  if (tid < HID) {
    const float xp = __int_as_float(s.pool[tid]);
    out[NUM_GRAPHS * OUTC + g * HID + tid] = xp;
    float p0 = xp * lw[tid * 2 + 0];
    float p1 = xp * lw[tid * 2 + 1];
    #pragma unroll
    for (int off = 32; off > 0; off >>= 1) {
      p0 += __shfl_down(p0, off);
      p1 += __shfl_down(p1, off);
    }
    if (tid == 0) {
      out[g * OUTC + 0] = p0 + lb[0];
      out[g * OUTC + 1] = p1 + lb[1];
    }
  }
}

// ============ fallback (ws too small): fused kernel, inline W convert ============
struct __align__(16) SmemF {
  unsigned char adj[208 * APITCH];
  unsigned short hpT[HID * HPITCH];
  float dinv[NPG];
  int cnt[NPG];
  int pool[HID];
};

__global__ __launch_bounds__(512, 4)
void gcn_fused_fb(const float* __restrict__ x,
                  const int* __restrict__ ei,
                  const float* __restrict__ cw,
                  const float* __restrict__ cb,
                  const float* __restrict__ lw,
                  const float* __restrict__ lb,
                  float* __restrict__ out,
                  int Etot) {
  __shared__ SmemF s;
  const int g = blockIdx.x;
  const int tid = threadIdx.x;
  const int base = g * NPG;
  const int ebase = g * EPG;
  const int lane = tid & 63;
  const int w = __builtin_amdgcn_readfirstlane(tid >> 6);
  const int ml = tid & 15;
  const int q  = (tid >> 4) & 3;

  {
    uint4* z = (uint4*)&s;
    const uint4 z4 = {0u, 0u, 0u, 0u};
    #pragma unroll
    for (int i = 0; i < 10; ++i) {
      int idx = tid + i * 512;
      if (idx < (208 * APITCH + HID * HPITCH * 2) / 16) z[idx] = z4;
    }
    if (tid < NPG) s.cnt[tid] = 0;
    if (tid < HID) s.pool[tid] = 0;
  }
  __syncthreads();

  int esrc[7], edst[7];
  #pragma unroll
  for (int r = 0; r < 7; ++r) {
    int e = tid + r * 512;
    esrc[r] = -1; edst[r] = 0;
    if (e < EPG) {
      esrc[r] = ei[ebase + e] - base;
      edst[r] = ei[Etot + ebase + e] - base;
      atomicAdd(&s.cnt[edst[r]], 1);
    }
  }
  __syncthreads();

  if (tid < NPG) s.dinv[tid] = rsqrtf((float)(s.cnt[tid] + 1));

  {
    unsigned* adjW = (unsigned*)s.adj;
    #pragma unroll
    for (int r = 0; r < 7; ++r) {
      if (esrc[r] >= 0) {
        int idx = edst[r] * APITCH + esrc[r];
        atomicAdd(&adjW[idx >> 2], 1u << ((idx & 3) * 8));
      }
    }
    if (tid < NPG) {
      int idx = tid * APITCH + tid;
      atomicAdd(&adjW[idx >> 2], 1u << ((idx & 3) * 8));
    }
  }
  __syncthreads();

  {
    int mts[2];
    mts[0] = w;
    mts[1] = (w < 5) ? 8 + w : -1;
    v4f acc[2][4];
    #pragma unroll
    for (int a = 0; a < 2; ++a)
      #pragma unroll
      for (int b = 0; b < 4; ++b)
        acc[a][b] = (v4f){0.f, 0.f, 0.f, 0.f};

    for (int kt = 0; kt < 7; ++kt) {
      const int k0 = kt * 32 + q * 8;
      const bool kok = (k0 < NROIS);
      v8s bhi[4], blo[4];
      #pragma unroll
      for (int nt = 0; nt < 4; ++nt) {
        #pragma unroll
        for (int i = 0; i < 8; ++i) {
          float f = kok ? cw[(k0 + i) * HID + nt * 16 + ml] : 0.f;
          unsigned hb = bf16_rne(f);
          float lo = f - __uint_as_float(hb << 16);
          bhi[nt][i] = (short)hb;
          blo[nt][i] = (short)(__float_as_uint(lo) >> 16);
        }
      }
      #pragma unroll
      for (int mi = 0; mi < 2; ++mi) {
        if (mts[mi] >= 0) {
          const int row = mts[mi] * 16 + ml;
          v8s ahi, alo;
          if (kok && row < NPG) {
            const float* px = x + (size_t)(base + row) * NROIS + k0;
            const float4 f0 = *(const float4*)px;
            const float4 f1 = *(const float4*)(px + 4);
            const float ff[8] = {f0.x, f0.y, f0.z, f0.w, f1.x, f1.y, f1.z, f1.w};
            #pragma unroll
            for (int i = 0; i < 8; ++i) {
              unsigned u = __float_as_uint(ff[i]);
              unsigned hb = u >> 16;
              float lo = ff[i] - __uint_as_float(hb << 16);
              ahi[i] = (short)hb;
              alo[i] = (short)(__float_as_uint(lo) >> 16);
            }
          } else {
            #pragma unroll
            for (int i = 0; i < 8; ++i) { ahi[i] = 0; alo[i] = 0; }
          }
          #pragma unroll
          for (int nt = 0; nt < 4; ++nt) {
            acc[mi][nt] = __builtin_amdgcn_mfma_f32_16x16x32_bf16(ahi, blo[nt], acc[mi][nt], 0, 0, 0);
            acc[mi][nt] = __builtin_amdgcn_mfma_f32_16x16x32_bf16(alo, bhi[nt], acc[mi][nt], 0, 0, 0);
            acc[mi][nt] = __builtin_amdgcn_mfma_f32_16x16x32_bf16(ahi, bhi[nt], acc[mi][nt], 0, 0, 0);
          }
        }
      }
    }
    #pragma unroll
    for (int mi = 0; mi < 2; ++mi) {
      if (mts[mi] >= 0) {
        #pragma unroll
        for (int r = 0; r < 4; ++r) {
          const int row = mts[mi] * 16 + q * 4 + r;
          if (row < NPG) {
            const float dv = s.dinv[row];
            #pragma unroll
            for (int nt = 0; nt < 4; ++nt)
              s.hpT[(nt * 16 + ml) * HPITCH + row] =
                  (unsigned short)bf16_rne(dv * acc[mi][nt][r]);
          }
        }
      }
    }
  }
  __syncthreads();

  {
    int mts[2];
    mts[0] = w;
    mts[1] = (w < 5) ? 8 + w : -1;
    v4f acc2[2][4];
    #pragma unroll
    for (int a = 0; a < 2; ++a)
      #pragma unroll
      for (int b = 0; b < 4; ++b)
        acc2[a][b] = (v4f){0.f, 0.f, 0.f, 0.f};

    for (int kt = 0; kt < 7; ++kt) {
      const int k0 = kt * 32 + q * 8;
      v8s bf[4];
      #pragma unroll
      for (int nt = 0; nt < 4; ++nt)
        bf[nt] = *(const v8s*)&s.hpT[(nt * 16 + ml) * HPITCH + k0];
      #pragma unroll
      for (int mi = 0; mi < 2; ++mi) {
        if (mts[mi] >= 0) {
          const int row = mts[mi] * 16 + ml;
          const uint2 dd = *(const uint2*)&s.adj[row * APITCH + k0];
          v8s af;
          #pragma unroll
          for (int i = 0; i < 4; ++i) {
            af[i]     = (short)(__float_as_uint((float)((dd.x >> (8 * i)) & 0xffu)) >> 16);
            af[i + 4] = (short)(__float_as_uint((float)((dd.y >> (8 * i)) & 0xffu)) >> 16);
          }
          #pragma unroll
          for (int nt = 0; nt < 4; ++nt)
            acc2[mi][nt] = __builtin_amdgcn_mfma_f32_16x16x32_bf16(af, bf[nt], acc2[mi][nt], 0, 0, 0);
        }
      }
    }

    float cbv[4];
    #pragma unroll
    for (int nt = 0; nt < 4; ++nt) cbv[nt] = cb[nt * 16 + ml];
    float mx[4] = {0.f, 0.f, 0.f, 0.f};
    #pragma unroll
    for (int mi = 0; mi < 2; ++mi) {
      if (mts[mi] >= 0) {
        #pragma unroll
        for (int r = 0; r < 4; ++r) {
          const int row = mts[mi] * 16 + q * 4 + r;
          if (row < NPG) {
            const float dv = s.dinv[row];
            #pragma unroll
            for (int nt = 0; nt < 4; ++nt) {
              float v = fmaxf(fmaf(dv, acc2[mi][nt][r], cbv[nt]), 0.f);
              mx[nt] = fmaxf(mx[nt], v);
            }
          }
        }
      }
    }
    #pragma unroll
    for (int nt = 0; nt < 4; ++nt) {
      mx[nt] = fmaxf(mx[nt], __shfl_xor(mx[nt], 16));
      mx[nt] = fmaxf(mx[nt], __shfl_xor(mx[nt], 32));
    }
    if (q == 0 && (lane >> 5) == 0) {
      #pragma unroll
      for (int nt = 0; nt < 4; ++nt)
        atomicMax(&s.pool[nt * 16 + ml], __float_as_int(mx[nt]));
    }
  }
  __syncthreads();

  if (tid < HID) {
    const float xp = __int_as_float(s.pool[tid]);
    out[NUM_GRAPHS * OUTC + g * HID + tid] = xp;
    float p0 = xp * lw[tid * 2 + 0];
    float p1 = xp * lw[tid * 2 + 1];
    #pragma unroll
    for (int off = 32; off > 0; off >>= 1) {
      p0 += __shfl_down(p0, off);
      p1 += __shfl_down(p1, off);
    }
    if (tid == 0) {
      out[g * OUTC + 0] = p0 + lb[0];
      out[g * OUTC + 1] = p1 + lb[1];
    }
  }
}

extern "C" void kernel_launch(void* const* d_in, const int* in_sizes, int n_in,
                              void* d_out, int out_size, void* d_ws, size_t ws_size,
                              hipStream_t stream) {
  const float* x  = (const float*)d_in[0];
  const int*   ei = (const int*)d_in[1];
  // d_in[2] = batch (node/200 by construction; unused)
  const float* cw = (const float*)d_in[3];
  const float* cb = (const float*)d_in[4];
  const float* lw = (const float*)d_in[5];
  const float* lb = (const float*)d_in[6];
  const int Etot = in_sizes[1] / 2;

  if (ws_size >= WS_NEEDED) {
    unsigned short* wimg = (unsigned short*)d_ws;
    prep_wimg<<<(WIMG_ELEMS + 255) / 256, 256, 0, stream>>>(cw, wimg);
    gcn_fused4<<<NUM_GRAPHS, 512, 0, stream>>>(x, ei, wimg, cb, lw, lb,
                                               (float*)d_out, Etot);
  } else {
    gcn_fused_fb<<<NUM_GRAPHS, 512, 0, stream>>>(x, ei, cw, cb, lw, lb,
                                                 (float*)d_out, Etot);
  }
}